// Round 7
// baseline (499.690 us; speedup 1.0000x reference)
//
#include <hip/hip_runtime.h>

#define SB 2
#define HH 8
#define SS 2048
#define DM 512
#define HD 64
#define SCALE 0.125f

typedef __attribute__((ext_vector_type(8))) short bfrag;   // 8 x bf16
typedef __attribute__((ext_vector_type(4))) float f4;

static __device__ __forceinline__ unsigned short f2bf(float x) {
  unsigned int u = __float_as_uint(x);
  unsigned int r = (u + 0x7FFFu + ((u >> 16) & 1u)) >> 16;
  return (unsigned short)r;
}
static __device__ __forceinline__ float bf2f(unsigned short s) {
  return __uint_as_float(((unsigned int)s) << 16);
}
static __device__ __forceinline__ void splitf(float x, short& hi, short& lo) {
  const unsigned u = __float_as_uint(x);
  hi = (short)(u >> 16);                                    // truncation
  lo = (short)f2bf(x - __uint_as_float(u & 0xFFFF0000u));   // RTNE residual
}

// ---------------- generic fp32 GEMM: C[M][N] = A[M][K] @ B[K][N] (+bias) ---
__global__ __launch_bounds__(256) void gemm_f32(const float* __restrict__ A,
                                                const float* __restrict__ Bm,
                                                const float* __restrict__ bias,
                                                float* __restrict__ C,
                                                int M, int N, int K) {
  __shared__ float As[16][68];   // [k][m], padded
  __shared__ float Bs[16][64];   // [k][n]
  const int t = threadIdx.x;
  const int nb = N >> 6;
  const int bm = blockIdx.x / nb, bn = blockIdx.x % nb;
  const int m0 = bm << 6, n0 = bn << 6;
  const int ty = t >> 4, tx = t & 15;
  const int mr = ty << 2, nc = tx << 2;
  const int am = t >> 2, akq = t & 3;
  const int bk = t >> 4, bnq = t & 15;
  float acc[4][4] = {};
  for (int k0 = 0; k0 < K; k0 += 16) {
    const float4 av = *(const float4*)&A[(size_t)(m0 + am) * K + k0 + (akq << 2)];
    const float4 bv = *(const float4*)&Bm[(size_t)(k0 + bk) * N + n0 + (bnq << 2)];
    __syncthreads();
    As[(akq << 2) + 0][am] = av.x;
    As[(akq << 2) + 1][am] = av.y;
    As[(akq << 2) + 2][am] = av.z;
    As[(akq << 2) + 3][am] = av.w;
    *(float4*)&Bs[bk][bnq << 2] = bv;
    __syncthreads();
#pragma unroll
    for (int kk = 0; kk < 16; ++kk) {
      float a[4], b[4];
      *(float4*)a = *(const float4*)&As[kk][mr];
      *(float4*)b = *(const float4*)&Bs[kk][nc];
#pragma unroll
      for (int i = 0; i < 4; ++i)
#pragma unroll
        for (int j = 0; j < 4; ++j) acc[i][j] += a[i] * b[j];
    }
  }
#pragma unroll
  for (int i = 0; i < 4; ++i) {
    float4 v = make_float4(acc[i][0], acc[i][1], acc[i][2], acc[i][3]);
    if (bias) {
      v.x += bias[n0 + nc + 0];
      v.y += bias[n0 + nc + 1];
      v.z += bias[n0 + nc + 2];
      v.w += bias[n0 + nc + 3];
    }
    *(float4*)&C[(size_t)(m0 + mr + i) * N + n0 + nc] = v;
  }
}

// -------- gemm_f32_vt: same compute, epilogue writes per-head transposed ---
__global__ __launch_bounds__(256) void gemm_f32_vt(const float* __restrict__ A,
                                                   const float* __restrict__ Bm,
                                                   unsigned short* __restrict__ VT,
                                                   int M, int N, int K) {
  __shared__ float As[16][68];
  __shared__ float Bs[16][64];
  const int t = threadIdx.x;
  const int nb = N >> 6;
  const int bm = blockIdx.x / nb, bn = blockIdx.x % nb;
  const int m0 = bm << 6, n0 = bn << 6;
  const int ty = t >> 4, tx = t & 15;
  const int mr = ty << 2, nc = tx << 2;
  const int am = t >> 2, akq = t & 3;
  const int bk = t >> 4, bnq = t & 15;
  float acc[4][4] = {};
  for (int k0 = 0; k0 < K; k0 += 16) {
    const float4 av = *(const float4*)&A[(size_t)(m0 + am) * K + k0 + (akq << 2)];
    const float4 bv = *(const float4*)&Bm[(size_t)(k0 + bk) * N + n0 + (bnq << 2)];
    __syncthreads();
    As[(akq << 2) + 0][am] = av.x;
    As[(akq << 2) + 1][am] = av.y;
    As[(akq << 2) + 2][am] = av.z;
    As[(akq << 2) + 3][am] = av.w;
    *(float4*)&Bs[bk][bnq << 2] = bv;
    __syncthreads();
#pragma unroll
    for (int kk = 0; kk < 16; ++kk) {
      float a[4], b[4];
      *(float4*)a = *(const float4*)&As[kk][mr];
      *(float4*)b = *(const float4*)&Bs[kk][nc];
#pragma unroll
      for (int i = 0; i < 4; ++i)
#pragma unroll
        for (int j = 0; j < 4; ++j) acc[i][j] += a[i] * b[j];
    }
  }
#pragma unroll
  for (int i = 0; i < 4; ++i) {
    const int row = m0 + mr + i;             // 0..4095
    const int bb = row >> 11, jr = row & 2047;
#pragma unroll
    for (int jx = 0; jx < 4; ++jx) {
      const int col = n0 + nc + jx;
      const int bh = bb * HH + (col >> 6), d = col & 63;
      VT[((size_t)bh * HD + d) * SS + jr] = f2bf(acc[i][jx]);
    }
  }
}

// -------- gemm_f32_khl: K projection, epilogue writes per-head hi/lo bf16 --
__global__ __launch_bounds__(256) void gemm_f32_khl(const float* __restrict__ A,
                                                    const float* __restrict__ Bm,
                                                    unsigned short* __restrict__ kh,
                                                    unsigned short* __restrict__ kl,
                                                    int M, int N, int K) {
  __shared__ float As[16][68];
  __shared__ float Bs[16][64];
  const int t = threadIdx.x;
  const int nb = N >> 6;
  const int bm = blockIdx.x / nb, bn = blockIdx.x % nb;
  const int m0 = bm << 6, n0 = bn << 6;
  const int ty = t >> 4, tx = t & 15;
  const int mr = ty << 2, nc = tx << 2;
  const int am = t >> 2, akq = t & 3;
  const int bk = t >> 4, bnq = t & 15;
  float acc[4][4] = {};
  for (int k0 = 0; k0 < K; k0 += 16) {
    const float4 av = *(const float4*)&A[(size_t)(m0 + am) * K + k0 + (akq << 2)];
    const float4 bv = *(const float4*)&Bm[(size_t)(k0 + bk) * N + n0 + (bnq << 2)];
    __syncthreads();
    As[(akq << 2) + 0][am] = av.x;
    As[(akq << 2) + 1][am] = av.y;
    As[(akq << 2) + 2][am] = av.z;
    As[(akq << 2) + 3][am] = av.w;
    *(float4*)&Bs[bk][bnq << 2] = bv;
    __syncthreads();
#pragma unroll
    for (int kk = 0; kk < 16; ++kk) {
      float a[4], b[4];
      *(float4*)a = *(const float4*)&As[kk][mr];
      *(float4*)b = *(const float4*)&Bs[kk][nc];
#pragma unroll
      for (int i = 0; i < 4; ++i)
#pragma unroll
        for (int j = 0; j < 4; ++j) acc[i][j] += a[i] * b[j];
    }
  }
#pragma unroll
  for (int i = 0; i < 4; ++i) {
    const int row = m0 + mr + i;             // 0..4095
    const int bb = row >> 11, jr = row & 2047;
#pragma unroll
    for (int jx = 0; jx < 4; ++jx) {
      const int col = n0 + nc + jx;
      const int bh = bb * HH + (col >> 6), d = col & 63;
      short hi, lo;
      splitf(acc[i][jx], hi, lo);
      const size_t o = ((size_t)bh * SS + jr) * HD + d;
      kh[o] = (unsigned short)hi;
      kl[o] = (unsigned short)lo;
    }
  }
}

// ---------------------------------------------------------------------------
// prep_evt: Ev fp32 [513][64] -> EvT bf16 [64][544] (transposed, zero-padded).
// ---------------------------------------------------------------------------
__global__ void prep_evt(const float* __restrict__ Ev, unsigned short* __restrict__ EvT) {
  const int idx = blockIdx.x * 256 + threadIdx.x;
  if (idx >= 64 * 544) return;
  const int d = idx / 544, r = idx % 544;
  EvT[idx] = (r < 513) ? f2bf(Ev[(size_t)r * HD + d]) : (unsigned short)0;
}

// ---------------------------------------------------------------------------
// attn_e: SINGLE-sweep attention. QK^T once; e = exp(l) UNNORMALIZED written
// (NT) to attn; z accumulated online; PV accumulated unnormalized and scaled
// by zi in the epilogue (row-uniform). zi written to zrow for norm_band.
// grid 2048 (16-row blocks, XCD swizzle), 4 waves = j-quarters.
// LDS 21.5 KB -> 7 blocks/CU (28 waves) to hide L2/L3 latency.
// ---------------------------------------------------------------------------
#define QK6(K0, K1, L0, L1, ACC)                                            \
  ACC = __builtin_amdgcn_mfma_f32_16x16x32_bf16(qh0, K0, ACC, 0, 0, 0);     \
  ACC = __builtin_amdgcn_mfma_f32_16x16x32_bf16(qh1, K1, ACC, 0, 0, 0);     \
  ACC = __builtin_amdgcn_mfma_f32_16x16x32_bf16(ql0, K0, ACC, 0, 0, 0);     \
  ACC = __builtin_amdgcn_mfma_f32_16x16x32_bf16(ql1, K1, ACC, 0, 0, 0);     \
  ACC = __builtin_amdgcn_mfma_f32_16x16x32_bf16(qh0, L0, ACC, 0, 0, 0);     \
  ACC = __builtin_amdgcn_mfma_f32_16x16x32_bf16(qh1, L1, ACC, 0, 0, 0);

__global__ __launch_bounds__(256, 6) void attn_e(
    const float* __restrict__ Qp,
    const unsigned short* __restrict__ khg,
    const unsigned short* __restrict__ klg,
    const unsigned short* __restrict__ VTg,
    const float* __restrict__ Ek,
    float* __restrict__ attn,
    float* __restrict__ concat,
    float* __restrict__ zrow) {
  // LDS 22016 B: qek [16][520]u16 (16640, aliased by pvb [4][16][64]f32 after
  // sync #2), wlds [4][16][40]u16 (5120), zbuf [4][16]f32 (256).
  __shared__ __attribute__((aligned(16))) char smem[22016];
  unsigned short (*qek_lds)[520] = (unsigned short(*)[520])smem;
  float (*pvb)[16][64] = (float(*)[16][64])smem;                     // alias
  unsigned short (*wlds)[16][40] = (unsigned short(*)[16][40])(smem + 16640);
  float (*zbuf)[16] = (float(*)[16])(smem + 21760);

  const int t = threadIdx.x;
  const int orig = blockIdx.x;
  const int wg = (orig & 7) * 256 + (orig >> 3);   // XCD swizzle (bijective)
  const int bh = wg >> 7, rb = wg & 127;
  const int b = bh >> 3, h = bh & 7;
  const int wv = t >> 6, lane = t & 63;
  const int ln = lane & 15, lq = lane >> 4;
  const int i0 = rb * 16;
  const int jbase = wv * 512;

  // Q fragments hi/lo for the block's 16 rows (same for all 4 waves)
  bfrag qh0, qh1, ql0, ql1;
  {
    const float* qrow = Qp + (size_t)(b * SS + i0 + ln) * DM + h * HD + lq * 8;
    const f4 x0 = *(const f4*)&qrow[0], x1 = *(const f4*)&qrow[4];
    const f4 x2 = *(const f4*)&qrow[32], x3 = *(const f4*)&qrow[36];
#pragma unroll
    for (int e = 0; e < 4; ++e) {
      short hi, lo;
      splitf(x0[e], hi, lo); qh0[e] = hi; ql0[e] = lo;
      splitf(x1[e], hi, lo); qh0[e + 4] = hi; ql0[e + 4] = lo;
      splitf(x2[e], hi, lo); qh1[e] = hi; ql1[e] = lo;
      splitf(x3[e], hi, lo); qh1[e + 4] = hi; ql1[e + 4] = lo;
    }
  }

  // qek fill (pre-scaled by SCALE), hi-part only; wave wv -> nt = wv, wv+4, ...
  for (int nt = wv; nt <= 32; nt += 4) {
    const int r = nt * 16 + ln;
    const int rc = r > 512 ? 512 : r;
    const float* erow = Ek + (size_t)rc * HD + lq * 8;
    const f4 a0 = *(const f4*)&erow[0], a1 = *(const f4*)&erow[4];
    const f4 a2 = *(const f4*)&erow[32], a3 = *(const f4*)&erow[36];
    bfrag e0, e1;
#pragma unroll
    for (int e = 0; e < 4; ++e) {
      e0[e] = (short)f2bf(a0[e]); e0[e + 4] = (short)f2bf(a1[e]);
      e1[e] = (short)f2bf(a2[e]); e1[e + 4] = (short)f2bf(a3[e]);
    }
    f4 acc = {0.f, 0.f, 0.f, 0.f};
    acc = __builtin_amdgcn_mfma_f32_16x16x32_bf16(qh0, e0, acc, 0, 0, 0);
    acc = __builtin_amdgcn_mfma_f32_16x16x32_bf16(qh1, e1, acc, 0, 0, 0);
    if (r < 513) {
#pragma unroll
      for (int rr = 0; rr < 4; ++rr)
        qek_lds[lq * 4 + rr][r] = f2bf(acc[rr] * SCALE);
    }
  }
  __syncthreads();   // #1: qek ready

  const unsigned short* khb = khg + (size_t)bh * SS * HD;
  const unsigned short* klb = klg + (size_t)bh * SS * HD;
  const unsigned short* vtb = VTg + (size_t)bh * HD * SS;
  const int row0 = i0 + lq * 4;
  const int rloc0 = lq * 4;
  const size_t base0 = (size_t)(jbase + ln) * HD + lq * 8;

  float zz[4] = {0.f, 0.f, 0.f, 0.f};
  f4 pv[4] = {{0.f,0.f,0.f,0.f},{0.f,0.f,0.f,0.f},{0.f,0.f,0.f,0.f},{0.f,0.f,0.f,0.f}};
  {
    bfrag k0 = *(const bfrag*)(khb + base0);
    bfrag k1 = *(const bfrag*)(khb + base0 + 32);
    bfrag l0 = *(const bfrag*)(klb + base0);
    bfrag l1 = *(const bfrag*)(klb + base0 + 32);
    bfrag vb0, vb1, vb2, vb3;
#pragma unroll 2
    for (int it = 0; it < 32; ++it) {
      const int itn = it < 31 ? it + 1 : 31;
      const size_t bn = base0 + (size_t)itn * 1024;
      const bfrag nk0 = *(const bfrag*)(khb + bn);
      const bfrag nk1 = *(const bfrag*)(khb + bn + 32);
      const bfrag nl0 = *(const bfrag*)(klb + bn);
      const bfrag nl1 = *(const bfrag*)(klb + bn + 32);
      const int s = it & 1;
      const int jc = jbase + (it >> 1) * 32;
      if (s == 0) {   // V fragments for this 32-col chunk
        const size_t vo = (size_t)ln * SS + jc + lq * 8;
        vb0 = *(const bfrag*)&vtb[vo];
        vb1 = *(const bfrag*)&vtb[vo + (size_t)16 * SS];
        vb2 = *(const bfrag*)&vtb[vo + (size_t)32 * SS];
        vb3 = *(const bfrag*)&vtb[vo + (size_t)48 * SS];
      }
      f4 acc = {0.f, 0.f, 0.f, 0.f};
      QK6(k0, k1, l0, l1, acc)
      const int j = jc + s * 16 + ln;
      const int jb2 = j - row0;
#pragma unroll
      for (int r = 0; r < 4; ++r) {
        int idx = jb2 - r + 256;
        idx = idx < 0 ? 0 : (idx > 512 ? 512 : idx);
        const float qv = bf2f(qek_lds[rloc0 + r][idx]);
        const float e = __expf(fmaf(acc[r], SCALE, qv));   // UNNORMALIZED
        zz[r] += e;
        __builtin_nontemporal_store(e, &attn[((size_t)bh * SS + row0 + r) * SS + j]);
        wlds[wv][lq * 4 + r][s * 16 + ln] = f2bf(e);
      }
      if (s == 1) {
        const bfrag pa = *(const bfrag*)&wlds[wv][ln][lq * 8];
        pv[0] = __builtin_amdgcn_mfma_f32_16x16x32_bf16(pa, vb0, pv[0], 0, 0, 0);
        pv[1] = __builtin_amdgcn_mfma_f32_16x16x32_bf16(pa, vb1, pv[1], 0, 0, 0);
        pv[2] = __builtin_amdgcn_mfma_f32_16x16x32_bf16(pa, vb2, pv[2], 0, 0, 0);
        pv[3] = __builtin_amdgcn_mfma_f32_16x16x32_bf16(pa, vb3, pv[3], 0, 0, 0);
      }
      k0 = nk0; k1 = nk1; l0 = nl0; l1 = nl1;
    }
  }
  // z: reduce over ln within 16-lane groups, publish per-quarter partials
#pragma unroll
  for (int r = 0; r < 4; ++r)
#pragma unroll
    for (int o = 1; o < 16; o <<= 1) zz[r] += __shfl_xor(zz[r], o);
  if (ln == 0) {
#pragma unroll
    for (int r = 0; r < 4; ++r) zbuf[wv][lq * 4 + r] = zz[r];
  }
  __syncthreads();   // #2 (qek reads done -> pvb alias safe)
  float zi[4];
#pragma unroll
  for (int r = 0; r < 4; ++r)
    zi[r] = 1.f / (zbuf[0][lq * 4 + r] + zbuf[1][lq * 4 + r] +
                   zbuf[2][lq * 4 + r] + zbuf[3][lq * 4 + r]);
  if (wv == 0 && ln == 0) {
#pragma unroll
    for (int r = 0; r < 4; ++r) zrow[(size_t)bh * SS + i0 + lq * 4 + r] = zi[r];
  }
  // scale pv by zi (row-uniform) and merge via LDS
#pragma unroll
  for (int dt = 0; dt < 4; ++dt)
#pragma unroll
    for (int r = 0; r < 4; ++r)
      pvb[wv][lq * 4 + r][dt * 16 + ln] = pv[dt][r] * zi[r];
  __syncthreads();   // #3
  {
    const int dt = wv;   // each wave writes one 16-col d-slice
#pragma unroll
    for (int r = 0; r < 4; ++r) {
      const int rl = lq * 4 + r;
      const float sum = pvb[0][rl][dt * 16 + ln] + pvb[1][rl][dt * 16 + ln] +
                        pvb[2][rl][dt * 16 + ln] + pvb[3][rl][dt * 16 + ln];
      concat[(size_t)(b * SS + i0 + rl) * DM + h * HD + dt * 16 + ln] = sum;
    }
  }
}

// ---------------------------------------------------------------------------
// norm_band: streaming normalize (w = e * zi, written back in place) + band
// extraction + band GEMM (wband @ EvT) added into concat.
// grid 2048 (16-row blocks, XCD swizzle), 4 waves = j-quarters.
// ---------------------------------------------------------------------------
__global__ __launch_bounds__(256) void norm_band(
    const float* __restrict__ zrow,
    const unsigned short* __restrict__ EvT,
    float* __restrict__ attn,
    float* __restrict__ concat) {
  __shared__ __attribute__((aligned(16))) unsigned short wband[16][552];
  __shared__ float lhb[4][16][2];

  const int t = threadIdx.x;
  const int orig = blockIdx.x;
  const int wg = (orig & 7) * 256 + (orig >> 3);
  const int bh = wg >> 7, rb = wg & 127;
  const int b = bh >> 3, h = bh & 7;
  const int wv = t >> 6, lane = t & 63;
  const int ln = lane & 15, lq = lane >> 4;
  const int i0 = rb * 16;
  const int jbase = wv * 512;

  {
    unsigned* wz = (unsigned*)&wband[0][0];
    for (int x = t; x < 16 * 552 / 2; x += 256) wz[x] = 0;
  }
  __syncthreads();   // #1: wband zeroed before any interior writes

  const int row = i0 + ln;
  const float zi = zrow[(size_t)bh * SS + row];
  float* arow = attn + ((size_t)bh * SS + row) * SS;
  float la = 0.f, ha = 0.f;
#pragma unroll 4
  for (int it = 0; it < 32; ++it) {
    const int c0 = jbase + it * 16 + lq * 4;
    const f4 v = *(const f4*)&arow[c0];
    f4 w;
#pragma unroll
    for (int e = 0; e < 4; ++e) w[e] = v[e] * zi;
    __builtin_nontemporal_store(w, (f4*)&arow[c0]);
#pragma unroll
    for (int e = 0; e < 4; ++e) {
      const int off = c0 + e - row;
      if (off <= -256) la += w[e];
      else if (off >= 256) ha += w[e];
      else wband[ln][off + 256] = f2bf(w[e]);
    }
  }
  // reduce bins over lanes sharing a row (lq groups: xor 16, 32)
  la += __shfl_xor(la, 16); la += __shfl_xor(la, 32);
  ha += __shfl_xor(ha, 16); ha += __shfl_xor(ha, 32);
  if (lane < 16) { lhb[wv][lane][0] = la; lhb[wv][lane][1] = ha; }
  __syncthreads();   // #2: wband interior + lhb complete

  if (t < 16) {
    float bl = 0.f, bhv = 0.f;
#pragma unroll
    for (int q = 0; q < 4; ++q) { bl += lhb[q][t][0]; bhv += lhb[q][t][1]; }
    wband[t][0] = f2bf(bl);
    wband[t][512] = f2bf(bhv);
  }
  __syncthreads();   // #3: bins in wband

  // band GEMM: wave wv handles d-slice dt = wv
  {
    const int dt = wv;
    f4 acc2 = {0.f, 0.f, 0.f, 0.f};
#pragma unroll 1
    for (int kt = 0; kt < 17; ++kt) {
      const bfrag a = *(const bfrag*)&wband[ln][kt * 32 + lq * 8];
      const bfrag bb = *(const bfrag*)&EvT[(size_t)(dt * 16 + ln) * 544 + kt * 32 + lq * 8];
      acc2 = __builtin_amdgcn_mfma_f32_16x16x32_bf16(a, bb, acc2, 0, 0, 0);
    }
#pragma unroll
    for (int r = 0; r < 4; ++r) {
      float* p = &concat[(size_t)(b * SS + i0 + lq * 4 + r) * DM + h * HD + dt * 16 + ln];
      *p += acc2[r];
    }
  }
}

// ---------------------------------------------------------------------------
extern "C" void kernel_launch(void* const* d_in, const int* in_sizes, int n_in,
                              void* d_out, int out_size, void* d_ws, size_t ws_size,
                              hipStream_t stream) {
  (void)in_sizes; (void)n_in; (void)out_size; (void)ws_size;
  const float* query = (const float*)d_in[0];
  const float* value = (const float*)d_in[1];
  const float* Wq = (const float*)d_in[2];
  const float* Wk = (const float*)d_in[3];
  const float* Wv = (const float*)d_in[4];
  const float* Wo = (const float*)d_in[5];
  const float* bo = (const float*)d_in[6];
  const float* Ek = (const float*)d_in[7];
  const float* Ev = (const float*)d_in[8];

  float* out = (float*)d_out;
  float* attn = out + (size_t)SB * SS * DM;

  // workspace carve — 29.56 MB total (29.43 proven; +131 KB zrow)
  char* wsb = (char*)d_ws;
  float* Qp = (float*)(wsb + 0);                             //  8 MB
  float* concat = (float*)(wsb + 8388608);                   //  8 MB
  unsigned short* kb16h = (unsigned short*)(wsb + 16777216); //  4 MB
  unsigned short* kb16l = (unsigned short*)(wsb + 20971520); //  4 MB
  unsigned short* VT = (unsigned short*)(wsb + 25165824);    //  4 MB
  unsigned short* EvT = (unsigned short*)(wsb + 29360128);   //  68 KB
  float* zrow = (float*)(wsb + 29429760);                    // 128 KB

  const int M = SB * SS;  // 4096
  dim3 blk(256);
  dim3 ggrid((M / 64) * (DM / 64));  // 512

  gemm_f32<<<ggrid, blk, 0, stream>>>(query, Wq, nullptr, Qp, M, DM, DM);
  gemm_f32_khl<<<ggrid, blk, 0, stream>>>(value, Wk, kb16h, kb16l, M, DM, DM);
  gemm_f32_vt<<<ggrid, blk, 0, stream>>>(value, Wv, VT, M, DM, DM);
  prep_evt<<<136, blk, 0, stream>>>(Ev, EvT);
  attn_e<<<2048, blk, 0, stream>>>(Qp, kb16h, kb16l, VT, Ek, attn, concat, zrow);
  norm_band<<<2048, blk, 0, stream>>>(zrow, EvT, attn, concat);
  gemm_f32<<<ggrid, blk, 0, stream>>>(concat, Wo, bo, out, M, DM, DM);
}